// Round 1
// baseline (1389.797 us; speedup 1.0000x reference)
//
#include <hip/hip_runtime.h>
#include <stdint.h>

// Problem constants (from setup_inputs): N=1e6, C=96, coords in [0,256).
#define CHAN 96
#define KEY_BITS 29
#define KEY_WORDS (1u << 23)        // 2^29 bits / 64 bits per word = 8,388,608 words
#define SCAN_BLOCKS 8192            // 8192 blocks * 1024 words = KEY_WORDS
#define WORDS_PER_BLOCK 1024        // 256 threads * 4 words

// key = (batch<<21) | ((x>>1)<<14) | ((y>>1)<<7) | (z>>1)
// Order-preserving w.r.t. lexicographic order of (batch, x&~1, y&~1, z&~1).
__device__ __forceinline__ unsigned int make_key(int4 c) {
  return ((unsigned int)c.x << 21) |
         (((unsigned int)c.y >> 1) << 14) |
         (((unsigned int)c.z >> 1) << 7) |
         ((unsigned int)c.w >> 1);
}

__global__ void k_set_bits(const int4* __restrict__ coords, int N,
                           unsigned long long* __restrict__ bm) {
  int i = blockIdx.x * blockDim.x + threadIdx.x;
  if (i >= N) return;
  unsigned int key = make_key(coords[i]);
  atomicOr(&bm[key >> 6], 1ull << (key & 63u));
}

// Per-block popcount sums over 1024 words -> bs[block]
__global__ void k_block_sums(const unsigned long long* __restrict__ bm,
                             unsigned int* __restrict__ bs) {
  __shared__ unsigned int sh[256];
  int t = threadIdx.x;
  size_t base = (size_t)blockIdx.x * WORDS_PER_BLOCK + (size_t)t * 4;
  unsigned int s = 0;
#pragma unroll
  for (int j = 0; j < 4; j++) s += (unsigned int)__popcll(bm[base + j]);
  sh[t] = s;
  __syncthreads();
  for (int off = 128; off > 0; off >>= 1) {
    if (t < off) sh[t] += sh[t + off];
    __syncthreads();
  }
  if (t == 0) bs[blockIdx.x] = sh[0];
}

// Exclusive scan of bs[8192] in place. One block, 256 threads, 32 elems/thread.
__global__ void k_scan_bs(unsigned int* __restrict__ bs) {
  __shared__ unsigned int sh[256];
  int t = threadIdx.x;
  unsigned int local[32];
  unsigned int sum = 0;
#pragma unroll
  for (int j = 0; j < 32; j++) { local[j] = bs[t * 32 + j]; sum += local[j]; }
  sh[t] = sum;
  __syncthreads();
  for (int off = 1; off < 256; off <<= 1) {
    unsigned int x = (t >= off) ? sh[t - off] : 0u;
    __syncthreads();
    sh[t] += x;
    __syncthreads();
  }
  unsigned int run = sh[t] - sum;  // exclusive prefix of this thread's chunk
#pragma unroll
  for (int j = 0; j < 32; j++) { bs[t * 32 + j] = run; run += local[j]; }
}

// Write global exclusive popcount prefix per word: wp[w]
__global__ void k_word_prefix(const unsigned long long* __restrict__ bm,
                              const unsigned int* __restrict__ bs,
                              unsigned int* __restrict__ wp) {
  __shared__ unsigned int sh[256];
  int t = threadIdx.x;
  size_t base = (size_t)blockIdx.x * WORDS_PER_BLOCK + (size_t)t * 4;
  unsigned int c[4];
  unsigned int sum = 0;
#pragma unroll
  for (int j = 0; j < 4; j++) { c[j] = (unsigned int)__popcll(bm[base + j]); sum += c[j]; }
  sh[t] = sum;
  __syncthreads();
  for (int off = 1; off < 256; off <<= 1) {
    unsigned int x = (t >= off) ? sh[t - off] : 0u;
    __syncthreads();
    sh[t] += x;
    __syncthreads();
  }
  unsigned int run = bs[blockIdx.x] + (sh[t] - sum);
#pragma unroll
  for (int j = 0; j < 4; j++) { wp[base + j] = run; run += c[j]; }
}

// Per point: compute sorted-unique rank, accumulate cnt/points atomics,
// record first-arrival writer, append stragglers to multi list.
__global__ void k_rank_scatter(const int4* __restrict__ coords,
                               const float* __restrict__ points,
                               const float* __restrict__ count, int N,
                               const unsigned long long* __restrict__ bm,
                               const unsigned int* __restrict__ wp,
                               unsigned int* __restrict__ writer,
                               unsigned int* __restrict__ npts,
                               unsigned int* __restrict__ nmulti,
                               unsigned long long* __restrict__ multi,
                               float* __restrict__ pts_out,
                               float* __restrict__ cnt_out) {
  int i = blockIdx.x * blockDim.x + threadIdx.x;
  if (i >= N) return;
  unsigned int key = make_key(coords[i]);
  unsigned int word = key >> 6, bit = key & 63u;
  unsigned long long w = bm[word];
  unsigned int rank = wp[word] + (unsigned int)__popcll(w & ((1ull << bit) - 1ull));

  unsigned int old = atomicAdd(&npts[rank], 1u);
  if (old == 0u) {
    writer[rank] = (unsigned int)i;  // unique first-arrival; no race
  } else {
    unsigned int slot = atomicAdd(nmulti, 1u);
    multi[slot] = ((unsigned long long)rank << 32) | (unsigned int)i;
  }
  float cn = count[i];
  atomicAdd(&cnt_out[rank], cn);
  atomicAdd(&pts_out[(size_t)rank * 3 + 0], cn * points[(size_t)i * 3 + 0]);
  atomicAdd(&pts_out[(size_t)rank * 3 + 1], cn * points[(size_t)i * 3 + 1]);
  atomicAdd(&pts_out[(size_t)rank * 3 + 2], cn * points[(size_t)i * 3 + 2]);
}

// Rows: copy representative feats (or zeros), divide centroid by count.
// block = (96, 2): threadIdx.x = channel, threadIdx.y = row within block.
__global__ void k_finalize(const float* __restrict__ feats,
                           const unsigned int* __restrict__ writer,
                           float* __restrict__ feats_out,
                           float* __restrict__ pts_out,
                           const float* __restrict__ cnt_out, int N) {
  int r = blockIdx.x * 2 + threadIdx.y;
  if (r >= N) return;
  int c = threadIdx.x;
  float cnt = cnt_out[r];
  float v = 0.f;
  if (cnt > 0.f) {  // cnt>0 implies npts>0 implies writer[r] valid
    unsigned int wsrc = writer[r];
    v = feats[(size_t)wsrc * CHAN + c];
  }
  feats_out[(size_t)r * CHAN + c] = v;
  if (c < 3) {
    float p = pts_out[(size_t)r * 3 + c];
    if (cnt > 0.f) p /= cnt;
    pts_out[(size_t)r * 3 + c] = p;
  }
}

__device__ __forceinline__ void atomic_max_float(float* addr, float val) {
  unsigned int* a = (unsigned int*)addr;
  unsigned int cur = *a;
  float curf = __uint_as_float(cur);
  while (val > curf) {
    unsigned int prev = atomicCAS(a, cur, __float_as_uint(val));
    if (prev == cur) break;
    cur = prev;
    curf = __uint_as_float(cur);
  }
}

// Merge non-representative points of multi-point cells (~0.1% of points).
__global__ void k_multi_max(const float* __restrict__ feats,
                            const float* __restrict__ cnt_out,
                            const unsigned int* __restrict__ nmulti,
                            const unsigned long long* __restrict__ multi,
                            float* __restrict__ feats_out) {
  unsigned int n = *nmulti;
  unsigned int stride = gridDim.x * blockDim.x;
  for (unsigned int idx = blockIdx.x * blockDim.x + threadIdx.x; idx < n; idx += stride) {
    unsigned long long e = multi[idx];
    unsigned int r = (unsigned int)(e >> 32);
    unsigned int i = (unsigned int)e;
    if (cnt_out[r] <= 0.f) continue;  // invalid rows stay zero
    for (int c = 0; c < CHAN; c++) {
      atomic_max_float(&feats_out[(size_t)r * CHAN + c], feats[(size_t)i * CHAN + c]);
    }
  }
}

extern "C" void kernel_launch(void* const* d_in, const int* in_sizes, int n_in,
                              void* d_out, int out_size, void* d_ws, size_t ws_size,
                              hipStream_t stream) {
  const int4* coords  = (const int4*)d_in[0];
  const float* feats  = (const float*)d_in[1];
  const float* points = (const float*)d_in[2];
  const float* count  = (const float*)d_in[3];
  const int N = in_sizes[3];  // count has N elements

  // Workspace layout (~112 MB):
  char* ws = (char*)d_ws;
  unsigned long long* bm = (unsigned long long*)ws;                      // 64 MB
  unsigned int* wp = (unsigned int*)(ws + (size_t)KEY_WORDS * 8);        // 32 MB
  unsigned int* bs = wp + KEY_WORDS;                                     // 32 KB
  unsigned long long* multi = (unsigned long long*)(bs + SCAN_BLOCKS);   // 8 MB (8-aligned)
  unsigned int* writer = (unsigned int*)(multi + N);                     // 4 MB
  unsigned int* npts = writer + N;                                       // 4 MB
  unsigned int* nmulti = npts + N;                                       // 4 B

  float* feats_out = (float*)d_out;
  float* pts_out = feats_out + (size_t)N * CHAN;
  float* cnt_out = pts_out + (size_t)N * 3;

  hipMemsetAsync(bm, 0, (size_t)KEY_WORDS * 8, stream);
  hipMemsetAsync(npts, 0, (size_t)N * 4 + 4, stream);      // npts + nmulti
  hipMemsetAsync(pts_out, 0, (size_t)N * 4 * 4, stream);   // pts_out(3N) + cnt_out(N)

  const int TB = 256;
  const int nb = (N + TB - 1) / TB;
  k_set_bits<<<nb, TB, 0, stream>>>(coords, N, bm);
  k_block_sums<<<SCAN_BLOCKS, 256, 0, stream>>>(bm, bs);
  k_scan_bs<<<1, 256, 0, stream>>>(bs);
  k_word_prefix<<<SCAN_BLOCKS, 256, 0, stream>>>(bm, bs, wp);
  k_rank_scatter<<<nb, TB, 0, stream>>>(coords, points, count, N, bm, wp,
                                        writer, npts, nmulti, multi, pts_out, cnt_out);
  dim3 fblock(CHAN, 2);
  k_finalize<<<(N + 1) / 2, fblock, 0, stream>>>(feats, writer, feats_out, pts_out, cnt_out, N);
  k_multi_max<<<128, 256, 0, stream>>>(feats, cnt_out, nmulti, multi, feats_out);
}

// Round 2
// 1128.931 us; speedup vs baseline: 1.2311x; 1.2311x over previous
//
#include <hip/hip_runtime.h>
#include <stdint.h>

// Problem constants (from setup_inputs): N=1e6, C=96, coords in [0,256).
#define CHAN 96
#define CHAN4 24                    // 96 floats = 24 float4
#define KEY_WORDS (1u << 23)        // 2^29 bits / 64 bits per word = 8,388,608 words
#define SCAN_BLOCKS 8192            // 8192 blocks * 1024 words = KEY_WORDS
#define WORDS_PER_BLOCK 1024        // 256 threads * 4 words

// key = (batch<<21) | ((x>>1)<<14) | ((y>>1)<<7) | (z>>1)
// Order-preserving w.r.t. lexicographic order of (batch, x&~1, y&~1, z&~1).
__device__ __forceinline__ unsigned int make_key(int4 c) {
  return ((unsigned int)c.x << 21) |
         (((unsigned int)c.y >> 1) << 14) |
         (((unsigned int)c.z >> 1) << 7) |
         ((unsigned int)c.w >> 1);
}

__global__ void k_set_bits(const int4* __restrict__ coords, int N,
                           unsigned long long* __restrict__ bm) {
  int i = blockIdx.x * blockDim.x + threadIdx.x;
  if (i >= N) return;
  unsigned int key = make_key(coords[i]);
  atomicOr(&bm[key >> 6], 1ull << (key & 63u));
}

// Per-block popcount sums over 1024 words -> bs[block]
__global__ void k_block_sums(const unsigned long long* __restrict__ bm,
                             unsigned int* __restrict__ bs) {
  __shared__ unsigned int sh[256];
  int t = threadIdx.x;
  size_t base = (size_t)blockIdx.x * WORDS_PER_BLOCK + (size_t)t * 4;
  unsigned int s = 0;
#pragma unroll
  for (int j = 0; j < 4; j++) s += (unsigned int)__popcll(bm[base + j]);
  sh[t] = s;
  __syncthreads();
  for (int off = 128; off > 0; off >>= 1) {
    if (t < off) sh[t] += sh[t + off];
    __syncthreads();
  }
  if (t == 0) bs[blockIdx.x] = sh[0];
}

// Exclusive scan of bs[8192] in place. One block, 256 threads, 32 elems/thread.
__global__ void k_scan_bs(unsigned int* __restrict__ bs) {
  __shared__ unsigned int sh[256];
  int t = threadIdx.x;
  unsigned int local[32];
  unsigned int sum = 0;
#pragma unroll
  for (int j = 0; j < 32; j++) { local[j] = bs[t * 32 + j]; sum += local[j]; }
  sh[t] = sum;
  __syncthreads();
  for (int off = 1; off < 256; off <<= 1) {
    unsigned int x = (t >= off) ? sh[t - off] : 0u;
    __syncthreads();
    sh[t] += x;
    __syncthreads();
  }
  unsigned int run = sh[t] - sum;  // exclusive prefix of this thread's chunk
#pragma unroll
  for (int j = 0; j < 32; j++) { bs[t * 32 + j] = run; run += local[j]; }
}

// Write global exclusive popcount prefix per word: wp[w]
__global__ void k_word_prefix(const unsigned long long* __restrict__ bm,
                              const unsigned int* __restrict__ bs,
                              unsigned int* __restrict__ wp) {
  __shared__ unsigned int sh[256];
  int t = threadIdx.x;
  size_t base = (size_t)blockIdx.x * WORDS_PER_BLOCK + (size_t)t * 4;
  unsigned int c[4];
  unsigned int sum = 0;
#pragma unroll
  for (int j = 0; j < 4; j++) { c[j] = (unsigned int)__popcll(bm[base + j]); sum += c[j]; }
  sh[t] = sum;
  __syncthreads();
  for (int off = 1; off < 256; off <<= 1) {
    unsigned int x = (t >= off) ? sh[t - off] : 0u;
    __syncthreads();
    sh[t] += x;
    __syncthreads();
  }
  unsigned int run = bs[blockIdx.x] + (sh[t] - sum);
#pragma unroll
  for (int j = 0; j < 4; j++) { wp[base + j] = run; run += c[j]; }
}

// Per point: compute sorted-unique rank, accumulate cnt/points atomics,
// record dest rank for first-arrival points, append stragglers to multi list.
__global__ void k_rank_scatter(const int4* __restrict__ coords,
                               const float* __restrict__ points,
                               const float* __restrict__ count, int N,
                               const unsigned long long* __restrict__ bm,
                               const unsigned int* __restrict__ wp,
                               unsigned int* __restrict__ dest_of_src,
                               unsigned int* __restrict__ npts,
                               unsigned int* __restrict__ nmulti,
                               unsigned long long* __restrict__ multi,
                               float* __restrict__ pts_out,
                               float* __restrict__ cnt_out) {
  int i = blockIdx.x * blockDim.x + threadIdx.x;
  if (i >= N) return;
  unsigned int key = make_key(coords[i]);
  unsigned int word = key >> 6, bit = key & 63u;
  unsigned long long w = bm[word];
  unsigned int rank = wp[word] + (unsigned int)__popcll(w & ((1ull << bit) - 1ull));

  unsigned int old = atomicAdd(&npts[rank], 1u);
  dest_of_src[i] = (old == 0u) ? rank : 0xFFFFFFFFu;
  if (old != 0u) {
    unsigned int slot = atomicAdd(nmulti, 1u);
    multi[slot] = ((unsigned long long)rank << 32) | (unsigned int)i;
  }
  float cn = count[i];
  atomicAdd(&cnt_out[rank], cn);
  atomicAdd(&pts_out[(size_t)rank * 3 + 0], cn * points[(size_t)i * 3 + 0]);
  atomicAdd(&pts_out[(size_t)rank * 3 + 1], cn * points[(size_t)i * 3 + 1]);
  atomicAdd(&pts_out[(size_t)rank * 3 + 2], cn * points[(size_t)i * 3 + 2]);
}

// Scatter copy: stream feats coalescedly (read side sequential), write each
// representative row to its destination rank. Stores need no latency hiding.
// block = (24, 8); each thread handles 2 source rows (independent chains).
__global__ void k_scatter_feats(const float4* __restrict__ feats4,
                                const unsigned int* __restrict__ dest_of_src,
                                float4* __restrict__ feats_out4, int N) {
  int c = threadIdx.x;  // float4 slot within row
#pragma unroll
  for (int j = 0; j < 2; j++) {
    int r = blockIdx.x * 16 + threadIdx.y + j * 8;
    if (r >= N) continue;
    unsigned int dest = dest_of_src[r];
    if (dest != 0xFFFFFFFFu) {
      float4 v = feats4[(size_t)r * CHAN4 + c];
      feats_out4[(size_t)dest * CHAN4 + c] = v;
    }
  }
}

// Per output row: zero feats of empty rows; divide centroid by count.
// block = (24, 8).
__global__ void k_fixrows(const unsigned int* __restrict__ npts,
                          const float* __restrict__ cnt_out,
                          float4* __restrict__ feats_out4,
                          float* __restrict__ pts_out, int N) {
  int r = blockIdx.x * 8 + threadIdx.y;
  if (r >= N) return;
  int c = threadIdx.x;
  unsigned int np = npts[r];
  if (np == 0u) {
    feats_out4[(size_t)r * CHAN4 + c] = make_float4(0.f, 0.f, 0.f, 0.f);
    // pts_out / cnt_out already zero from memset
  } else if (c < 3) {
    float cn = cnt_out[r];
    pts_out[(size_t)r * 3 + c] /= cn;
  }
}

__device__ __forceinline__ void atomic_max_float(float* addr, float val) {
  unsigned int* a = (unsigned int*)addr;
  unsigned int cur = *a;
  float curf = __uint_as_float(cur);
  while (val > curf) {
    unsigned int prev = atomicCAS(a, cur, __float_as_uint(val));
    if (prev == cur) break;
    cur = prev;
    curf = __uint_as_float(cur);
  }
}

// Merge non-representative points of multi-point cells (~0.1% of points).
__global__ void k_multi_max(const float* __restrict__ feats,
                            const unsigned int* __restrict__ nmulti,
                            const unsigned long long* __restrict__ multi,
                            float* __restrict__ feats_out) {
  unsigned int n = *nmulti;
  unsigned int stride = gridDim.x * blockDim.x;
  for (unsigned int idx = blockIdx.x * blockDim.x + threadIdx.x; idx < n; idx += stride) {
    unsigned long long e = multi[idx];
    unsigned int r = (unsigned int)(e >> 32);
    unsigned int i = (unsigned int)e;
    for (int c = 0; c < CHAN; c++) {
      atomic_max_float(&feats_out[(size_t)r * CHAN + c], feats[(size_t)i * CHAN + c]);
    }
  }
}

extern "C" void kernel_launch(void* const* d_in, const int* in_sizes, int n_in,
                              void* d_out, int out_size, void* d_ws, size_t ws_size,
                              hipStream_t stream) {
  const int4* coords  = (const int4*)d_in[0];
  const float* feats  = (const float*)d_in[1];
  const float* points = (const float*)d_in[2];
  const float* count  = (const float*)d_in[3];
  const int N = in_sizes[3];  // count has N elements

  // Workspace layout (~112 MB):
  char* ws = (char*)d_ws;
  unsigned long long* bm = (unsigned long long*)ws;                      // 64 MB
  unsigned int* wp = (unsigned int*)(ws + (size_t)KEY_WORDS * 8);        // 32 MB
  unsigned int* bs = wp + KEY_WORDS;                                     // 32 KB
  unsigned long long* multi = (unsigned long long*)(bs + SCAN_BLOCKS);   // 8 MB (8-aligned)
  unsigned int* dest_of_src = (unsigned int*)(multi + N);                // 4 MB
  unsigned int* npts = dest_of_src + N;                                  // 4 MB
  unsigned int* nmulti = npts + N;                                       // 4 B

  float* feats_out = (float*)d_out;
  float* pts_out = feats_out + (size_t)N * CHAN;
  float* cnt_out = pts_out + (size_t)N * 3;

  hipMemsetAsync(bm, 0, (size_t)KEY_WORDS * 8, stream);
  hipMemsetAsync(npts, 0, (size_t)N * 4 + 4, stream);      // npts + nmulti
  hipMemsetAsync(pts_out, 0, (size_t)N * 4 * 4, stream);   // pts_out(3N) + cnt_out(N)

  const int TB = 256;
  const int nb = (N + TB - 1) / TB;
  k_set_bits<<<nb, TB, 0, stream>>>(coords, N, bm);
  k_block_sums<<<SCAN_BLOCKS, 256, 0, stream>>>(bm, bs);
  k_scan_bs<<<1, 256, 0, stream>>>(bs);
  k_word_prefix<<<SCAN_BLOCKS, 256, 0, stream>>>(bm, bs, wp);
  k_rank_scatter<<<nb, TB, 0, stream>>>(coords, points, count, N, bm, wp,
                                        dest_of_src, npts, nmulti, multi, pts_out, cnt_out);
  dim3 cblock(CHAN4, 8);
  k_scatter_feats<<<(N + 15) / 16, cblock, 0, stream>>>(
      (const float4*)feats, dest_of_src, (float4*)feats_out, N);
  k_fixrows<<<(N + 7) / 8, cblock, 0, stream>>>(npts, cnt_out, (float4*)feats_out, pts_out, N);
  k_multi_max<<<128, 256, 0, stream>>>(feats, nmulti, multi, feats_out);
}